// Round 3
// baseline (636.840 us; speedup 1.0000x reference)
//
#include <hip/hip_runtime.h>

#define N_ROWS 65536
#define C_CLUST 512
#define D_DIM 256

// ---- workspace layout (float-index units) ----
#define WS_DICTT   0          // 256*512 = 131072 floats
#define WS_DSQ     131072     // 512
#define WS_XSQ     131584     // 65536
#define WS_CS      197120     // 512
#define WS_DCY     197632     // 512
#define WS_ISUM    198144     // 512*256 = 131072
#define WS_COUNTS  329216     // 512 uint
#define WS_OFFSETS 329728     // 513 uint
#define WS_FILL    330752     // 512 uint
#define WS_ROWLIST 331264     // 262144 uint

// ---- output layout (float-index units) ----
#define OUT_GEMB 0
#define OUT_TOPK 16777216
#define OUT_DICT 17039360
#define OUT_CSS  17170432
#define OUT_CV   17170944
#define OUT_CNUM 17302016

#define BM 128
#define BN 128
#define BK 16
#define ASTRIDE 132   // padded stride for As: breaks 4-way write conflict, keeps 16B align

#define RPB 128   // rowlist entries per block in cluster_sum2_k

// ---------- K-zero: zero counters + isum ----------
__global__ void zero_k(unsigned* counts, unsigned* fill, float* isum) {
    int t = blockIdx.x * blockDim.x + threadIdx.x;
    if (t < 512) { counts[t] = 0u; fill[t] = 0u; }
    if (t < C_CLUST * D_DIM) isum[t] = 0.f;
}

// ---------- K0: dict transpose + ||d||^2 ----------
__global__ void prep_dict(const float* __restrict__ dic, float* __restrict__ ws) {
    int c = blockIdx.x, k = threadIdx.x;
    float v = dic[c * D_DIM + k];
    ws[WS_DICTT + k * C_CLUST + c] = v;
    __shared__ float red[256];
    red[k] = v * v;
    __syncthreads();
    for (int s = 128; s > 0; s >>= 1) {
        if (k < s) red[k] += red[k + s];
        __syncthreads();
    }
    if (k == 0) ws[WS_DSQ + c] = red[0];
}

// ---------- K0b: ||x||^2 per row ----------
__global__ void row_sq(const float* __restrict__ x, float* __restrict__ ws) {
    int row = blockIdx.x, k = threadIdx.x;
    float v = x[row * D_DIM + k];
    __shared__ float red[256];
    red[k] = v * v;
    __syncthreads();
    for (int s = 128; s > 0; s >>= 1) {
        if (k < s) red[k] += red[k + s];
        __syncthreads();
    }
    if (k == 0) ws[WS_XSQ + row] = red[0];
}

// ---------- lexicographic (value, index) compare-exchange helpers ----------
__device__ __forceinline__ void lexCE(float& av, int& ai, float& bv, int& bi) {
    bool sw = (bv < av) || ((bv == av) && (bi < ai));
    float nv0 = sw ? bv : av; int ni0 = sw ? bi : ai;
    float nv1 = sw ? av : bv; int ni1 = sw ? ai : bi;
    av = nv0; ai = ni0; bv = nv1; bi = ni1;
}

// merge sorted quad a with sorted quad b -> a = sorted top-4 of union
__device__ __forceinline__ void merge4(
    float& a0v, int& a0i, float& a1v, int& a1i,
    float& a2v, int& a2i, float& a3v, int& a3i,
    float b0v, int b0i, float b1v, int b1i,
    float b2v, int b2i, float b3v, int b3i)
{
    // half-cleaner: mins of (a_k, b_{3-k}) = 4 smallest of union (bitonic)
    bool s0 = (b3v < a0v) || ((b3v == a0v) && (b3i < a0i));
    float m0v = s0 ? b3v : a0v; int m0i = s0 ? b3i : a0i;
    bool s1 = (b2v < a1v) || ((b2v == a1v) && (b2i < a1i));
    float m1v = s1 ? b2v : a1v; int m1i = s1 ? b2i : a1i;
    bool s2 = (b1v < a2v) || ((b1v == a2v) && (b1i < a2i));
    float m2v = s2 ? b1v : a2v; int m2i = s2 ? b1i : a2i;
    bool s3 = (b0v < a3v) || ((b0v == a3v) && (b0i < a3i));
    float m3v = s3 ? b0v : a3v; int m3i = s3 ? b0i : a3i;
    // bitonic sort-4
    lexCE(m0v, m0i, m2v, m2i);
    lexCE(m1v, m1i, m3v, m3i);
    lexCE(m0v, m0i, m1v, m1i);
    lexCE(m2v, m2i, m3v, m3i);
    a0v = m0v; a0i = m0i; a1v = m1v; a1i = m1i;
    a2v = m2v; a2i = m2i; a3v = m3v; a3i = m3i;
}

// ---------- K1: fused GEMM (distances) + register top-4 + histogram ----------
__global__ __launch_bounds__(256, 2) void gemm_topk(
    const float* __restrict__ x, const float* __restrict__ ws,
    float* __restrict__ out_topk, unsigned* __restrict__ counts)
{
    __shared__ float As[BK * ASTRIDE];   // 16 x 132 (128 rows used)
    __shared__ float Bs[BK * BN];        // 16 x 128
    __shared__ unsigned hist[512];

    const int tid = threadIdx.x;
    const int tx = tid & 15, ty = tid >> 4;
    const int rowBase = blockIdx.x * BM;
    const float* dictT = ws + WS_DICTT;
    const float* dsq = ws + WS_DSQ;
    const float* xsq = ws + WS_XSQ;

    for (int h = tid; h < 512; h += 256) hist[h] = 0u;

    // running top-4 for row (ty*8 + (tx&7)) — two redundant owner lanes per row
    float rv0 = 3.4e38f, rv1 = 3.4e38f, rv2 = 3.4e38f, rv3 = 3.4e38f;
    int ri0 = 0x7FFFFFFF, ri1 = 0x7FFFFFFF, ri2 = 0x7FFFFFFF, ri3 = 0x7FFFFFFF;

    for (int cc = 0; cc < C_CLUST / BN; ++cc) {
        float acc[8][8];
        #pragma unroll
        for (int i = 0; i < 8; ++i)
            #pragma unroll
            for (int j = 0; j < 8; ++j) acc[i][j] = 0.f;

        for (int kb = 0; kb < D_DIM / BK; ++kb) {
            __syncthreads();
            // stage A (transposed, padded stride): 128 rows x 16 k
            #pragma unroll
            for (int ii = 0; ii < 2; ++ii) {
                int q = tid + ii * 256;       // 512 float4s
                int r = q >> 2;
                int kk = (q & 3) << 2;
                const float4 v = *reinterpret_cast<const float4*>(
                    &x[(rowBase + r) * D_DIM + kb * BK + kk]);
                As[(kk + 0) * ASTRIDE + r] = v.x;
                As[(kk + 1) * ASTRIDE + r] = v.y;
                As[(kk + 2) * ASTRIDE + r] = v.z;
                As[(kk + 3) * ASTRIDE + r] = v.w;
            }
            // stage B: 16 k x 128 clusters (dictT is [D][C])
            #pragma unroll
            for (int ii = 0; ii < 2; ++ii) {
                int q = tid + ii * 256;
                int k = q >> 5;
                int c4 = (q & 31) << 2;
                *reinterpret_cast<float4*>(&Bs[k * BN + c4]) =
                    *reinterpret_cast<const float4*>(
                        &dictT[(kb * BK + k) * C_CLUST + cc * BN + c4]);
            }
            __syncthreads();
            #pragma unroll
            for (int k = 0; k < BK; ++k) {
                float a[8], b[8];
                float4 t0 = *reinterpret_cast<const float4*>(&As[k * ASTRIDE + ty * 8]);
                float4 t1 = *reinterpret_cast<const float4*>(&As[k * ASTRIDE + ty * 8 + 4]);
                // split B fragment: tx*4 and 64+tx*4 -> 2-way (free) instead of 4-way
                float4 u0 = *reinterpret_cast<const float4*>(&Bs[k * BN + tx * 4]);
                float4 u1 = *reinterpret_cast<const float4*>(&Bs[k * BN + 64 + tx * 4]);
                a[0]=t0.x; a[1]=t0.y; a[2]=t0.z; a[3]=t0.w;
                a[4]=t1.x; a[5]=t1.y; a[6]=t1.z; a[7]=t1.w;
                b[0]=u0.x; b[1]=u0.y; b[2]=u0.z; b[3]=u0.w;
                b[4]=u1.x; b[5]=u1.y; b[6]=u1.z; b[7]=u1.w;
                #pragma unroll
                for (int i = 0; i < 8; ++i)
                    #pragma unroll
                    for (int j = 0; j < 8; ++j)
                        acc[i][j] = fmaf(a[i], b[j], acc[i][j]);
            }
        }

        // ---- epilogue: per-row top-4 entirely in registers ----
        float ds[8];
        #pragma unroll
        for (int j = 0; j < 8; ++j) {
            int col = (j < 4) ? (tx * 4 + j) : (64 + tx * 4 + (j - 4));
            ds[j] = dsq[cc * BN + col];
        }
        #pragma unroll
        for (int i = 0; i < 8; ++i) {
            float xs = xsq[rowBase + ty * 8 + i];
            // local sorted top-4 of this thread's 8 columns (ascending idx visit
            // order + strict < reproduces lower-index-wins ties)
            float l0v = 3.4e38f, l1v = 3.4e38f, l2v = 3.4e38f, l3v = 3.4e38f;
            int l0i = 0x7FFFFFFF, l1i = 0x7FFFFFFF, l2i = 0x7FFFFFFF, l3i = 0x7FFFFFFF;
            #pragma unroll
            for (int j = 0; j < 8; ++j) {
                int col = (j < 4) ? (tx * 4 + j) : (64 + tx * 4 + (j - 4));
                int idx = cc * BN + col;
                float v = __fsub_rn(__fadd_rn(xs, ds[j]),
                                    __fmul_rn(2.0f, acc[i][j]));
                if (v < l3v) {
                    if (v < l2v) {
                        l3v = l2v; l3i = l2i;
                        if (v < l1v) {
                            l2v = l1v; l2i = l1i;
                            if (v < l0v) { l1v = l0v; l1i = l0i; l0v = v; l0i = idx; }
                            else { l1v = v; l1i = idx; }
                        } else { l2v = v; l2i = idx; }
                    } else { l3v = v; l3i = idx; }
                }
            }
            // butterfly merge across the 16 lanes sharing this row group
            #pragma unroll
            for (int mask = 1; mask <= 8; mask <<= 1) {
                float b0v = __shfl_xor(l0v, mask); int b0i = __shfl_xor(l0i, mask);
                float b1v = __shfl_xor(l1v, mask); int b1i = __shfl_xor(l1i, mask);
                float b2v = __shfl_xor(l2v, mask); int b2i = __shfl_xor(l2i, mask);
                float b3v = __shfl_xor(l3v, mask); int b3i = __shfl_xor(l3i, mask);
                merge4(l0v, l0i, l1v, l1i, l2v, l2i, l3v, l3i,
                       b0v, b0i, b1v, b1i, b2v, b2i, b3v, b3i);
            }
            // owner lanes fold tile result into running top-4
            if ((tx & 7) == i)
                merge4(rv0, ri0, rv1, ri1, rv2, ri2, rv3, ri3,
                       l0v, l0i, l1v, l1i, l2v, l2i, l3v, l3i);
        }
    }

    if (tx < 8) {
        int r = rowBase + ty * 8 + tx;
        out_topk[r * 4 + 0] = (float)ri0;
        out_topk[r * 4 + 1] = (float)ri1;
        out_topk[r * 4 + 2] = (float)ri2;
        out_topk[r * 4 + 3] = (float)ri3;
        atomicAdd(&hist[ri0], 1u);
        atomicAdd(&hist[ri1], 1u);
        atomicAdd(&hist[ri2], 1u);
        atomicAdd(&hist[ri3], 1u);
    }
    __syncthreads();
    for (int h = tid; h < 512; h += 256) {
        unsigned v = hist[h];
        if (v) atomicAdd(&counts[h], v);
    }
}

// ---------- K2: group_emb = mean of 4 dict rows, with STE rounding ----------
__global__ void group_emb_k(const float* __restrict__ x, const float* __restrict__ dic,
                            const float* __restrict__ topk, float* __restrict__ out)
{
    int row = blockIdx.x, d = threadIdx.x;
    int i0 = (int)topk[row * 4 + 0];
    int i1 = (int)topk[row * 4 + 1];
    int i2 = (int)topk[row * 4 + 2];
    int i3 = (int)topk[row * 4 + 3];
    float g = __fadd_rn(__fadd_rn(__fadd_rn(dic[i0 * D_DIM + d],
                                            dic[i1 * D_DIM + d]),
                                  dic[i2 * D_DIM + d]),
                        dic[i3 * D_DIM + d]);
    g = __fmul_rn(g, 0.25f);
    float xv = x[row * D_DIM + d];
    out[row * D_DIM + d] = __fadd_rn(__fsub_rn(g, xv), xv);
}

// ---------- K3: exclusive prefix sum of counts ----------
__global__ void prefix_k(const unsigned* __restrict__ counts, unsigned* __restrict__ offsets) {
    __shared__ unsigned s[512];
    int t = threadIdx.x;
    unsigned my = counts[t];
    s[t] = my;
    __syncthreads();
    for (int off = 1; off < 512; off <<= 1) {
        unsigned v = (t >= off) ? s[t - off] : 0u;
        __syncthreads();
        s[t] += v;
        __syncthreads();
    }
    offsets[t] = s[t] - my;
    if (t == 511) offsets[512] = s[511];
}

// ---------- K4: scatter rows into cluster buckets (packed (c<<16)|row) ----------
__global__ void scatter_k(const float* __restrict__ topk, const unsigned* __restrict__ offsets,
                          unsigned* __restrict__ fill, unsigned* __restrict__ rowlist) {
    int row = blockIdx.x * 256 + threadIdx.x;
    #pragma unroll
    for (int k = 0; k < 4; ++k) {
        int c = (int)topk[row * 4 + k];
        unsigned p = atomicAdd(&fill[c], 1u);
        rowlist[offsets[c] + p] = ((unsigned)c << 16) | (unsigned)row;
    }
}

// ---------- K5: load-balanced segmented sum (encodings^T @ X) ----------
__global__ __launch_bounds__(256, 8) void cluster_sum2_k(
    const float* __restrict__ x, const unsigned* __restrict__ rowlist,
    float* __restrict__ isum)
{
    const int d = threadIdx.x;
    const int base = blockIdx.x * RPB;
    unsigned e0 = rowlist[base];
    int ccur = (int)(e0 >> 16);
    float acc = 0.f;
    #pragma unroll 4
    for (int j = 0; j < RPB; ++j) {
        unsigned e = rowlist[base + j];
        int c = (int)(e >> 16);
        float v = x[(e & 0xFFFFu) * D_DIM + d];
        if (c != ccur) {
            atomicAdd(&isum[ccur * D_DIM + d], acc);
            acc = 0.f;
            ccur = c;
        }
        acc += v;
    }
    atomicAdd(&isum[ccur * D_DIM + d], acc);
}

// ---------- K6: sequential decay scan + css EMA + laplace ----------
__global__ void ema_scalar_k(const float* __restrict__ css_in, const float* __restrict__ cnum_in,
                             const unsigned* __restrict__ counts,
                             float* __restrict__ ws, float* __restrict__ out) {
    __shared__ float sdecay[512];
    __shared__ float sred[512];
    __shared__ float scn[512];
    __shared__ unsigned smask[512];
    int t = threadIdx.x; // 512 threads
    unsigned cnt = counts[t];
    float size = (float)cnt;
    float mask = (cnt != 0u) ? 1.f : 0.f;
    float cnum_new = __fadd_rn(cnum_in[t], mask);
    scn[t] = cnum_new;
    smask[t] = cnt;
    __syncthreads();
    if (t == 0) {
        float d = 0.99f;
        for (int c = 0; c < 512; ++c) {
            if (smask[c] != 0u && scn[c] <= 10.0f)
                d = __fmul_rn(d, scn[c]) / 10.0f;   // (decay*c)/10, IEEE div
            sdecay[c] = d;
        }
    }
    __syncthreads();
    float d = sdecay[t];
    float css = css_in[t];
    float css_new = (cnt != 0u)
        ? __fadd_rn(__fmul_rn(css, d), __fmul_rn(size, __fsub_rn(1.f, d)))
        : css;
    out[OUT_CSS + t] = css_new;
    out[OUT_CNUM + t] = cnum_new;
    sred[t] = css_new;
    __syncthreads();
    for (int s = 256; s > 0; s >>= 1) {
        if (t < s) sred[t] += sred[t + s];
        __syncthreads();
    }
    float S = sred[0];
    float cs = __fmul_rn(__fdiv_rn(__fadd_rn(css_new, 1e-5f),
                                   __fadd_rn(S, 0.00512f)), S);
    ws[WS_CS + t] = cs;
    ws[WS_DCY + t] = d;
}

// ---------- K7: cluster_value EMA + dictionary normalize ----------
__global__ void final_k(const float* __restrict__ cv_in, const float* __restrict__ ws,
                        const unsigned* __restrict__ counts, float* __restrict__ out) {
    int c = blockIdx.x, d = threadIdx.x;
    float isum = ws[WS_ISUM + c * D_DIM + d];
    float dc = ws[WS_DCY + c];
    float cs = ws[WS_CS + c];
    unsigned cnt = counts[c];
    float cv = cv_in[c * D_DIM + d];
    float cvn = (cnt != 0u)
        ? __fadd_rn(__fmul_rn(cv, dc), __fmul_rn(isum, __fsub_rn(1.f, dc)))
        : cv;
    out[OUT_CV + c * D_DIM + d] = cvn;
    out[OUT_DICT + c * D_DIM + d] = (cnt != 0u) ? __fdiv_rn(cvn, cs) : cvn;
}

extern "C" void kernel_launch(void* const* d_in, const int* in_sizes, int n_in,
                              void* d_out, int out_size, void* d_ws, size_t ws_size,
                              hipStream_t stream) {
    const float* x       = (const float*)d_in[0];
    const float* dic     = (const float*)d_in[1];
    const float* css_in  = (const float*)d_in[2];
    const float* cv_in   = (const float*)d_in[3];
    const float* cnum_in = (const float*)d_in[4];
    float* out = (float*)d_out;
    float* ws  = (float*)d_ws;
    unsigned* counts  = (unsigned*)(ws + WS_COUNTS);
    unsigned* offsets = (unsigned*)(ws + WS_OFFSETS);
    unsigned* fill    = (unsigned*)(ws + WS_FILL);
    unsigned* rowlist = (unsigned*)(ws + WS_ROWLIST);

    zero_k<<<C_CLUST * D_DIM / 256, 256, 0, stream>>>(counts, fill, ws + WS_ISUM);
    prep_dict<<<C_CLUST, 256, 0, stream>>>(dic, ws);
    row_sq<<<N_ROWS, 256, 0, stream>>>(x, ws);

    gemm_topk<<<N_ROWS / BM, 256, 0, stream>>>(x, ws, out + OUT_TOPK, counts);

    group_emb_k<<<N_ROWS, 256, 0, stream>>>(x, dic, out + OUT_TOPK, out + OUT_GEMB);
    prefix_k<<<1, 512, 0, stream>>>(counts, offsets);
    scatter_k<<<N_ROWS / 256, 256, 0, stream>>>(out + OUT_TOPK, offsets, fill, rowlist);
    cluster_sum2_k<<<N_ROWS * 4 / RPB, 256, 0, stream>>>(x, rowlist, ws + WS_ISUM);
    ema_scalar_k<<<1, 512, 0, stream>>>(css_in, cnum_in, counts, ws, out);
    final_k<<<C_CLUST, 256, 0, stream>>>(cv_in, ws, counts, out);
}

// Round 4
// 623.711 us; speedup vs baseline: 1.0210x; 1.0210x over previous
//
#include <hip/hip_runtime.h>

#define N_ROWS 65536
#define C_CLUST 512
#define D_DIM 256

// ---- workspace layout (float-index units) ----
#define WS_DICTT   0          // 256*512 = 131072 floats
#define WS_DSQ     131072     // 512
#define WS_XSQ     131584     // 65536
#define WS_CS      197120     // 512
#define WS_DCY     197632     // 512
#define WS_ISUM    198144     // 512*256 = 131072
#define WS_COUNTS  329216     // 512 uint
#define WS_OFFSETS 329728     // 513 uint
#define WS_FILL    330752     // 512 uint
#define WS_ROWLIST 331264     // 262144 uint

// ---- output layout (float-index units) ----
#define OUT_GEMB 0
#define OUT_TOPK 16777216
#define OUT_DICT 17039360
#define OUT_CSS  17170432
#define OUT_CV   17170944
#define OUT_CNUM 17302016

#define BM 128
#define BN 128
#define BK 16
#define ASTRIDE 132   // padded stride for As: 2-way (free) write conflicts only

#define RPB 128   // rowlist entries per block in cluster_sum2_k

// ---------- K-zero: zero counters + isum ----------
__global__ void zero_k(unsigned* counts, unsigned* fill, float* isum) {
    int t = blockIdx.x * blockDim.x + threadIdx.x;
    if (t < 512) { counts[t] = 0u; fill[t] = 0u; }
    if (t < C_CLUST * D_DIM) isum[t] = 0.f;
}

// ---------- K0: dict transpose + ||d||^2 ----------
__global__ void prep_dict(const float* __restrict__ dic, float* __restrict__ ws) {
    int c = blockIdx.x, k = threadIdx.x;
    float v = dic[c * D_DIM + k];
    ws[WS_DICTT + k * C_CLUST + c] = v;
    __shared__ float red[256];
    red[k] = v * v;
    __syncthreads();
    for (int s = 128; s > 0; s >>= 1) {
        if (k < s) red[k] += red[k + s];
        __syncthreads();
    }
    if (k == 0) ws[WS_DSQ + c] = red[0];
}

// ---------- K0b: ||x||^2 per row (unchanged: keeps xsq bit-identical) ----------
__global__ void row_sq(const float* __restrict__ x, float* __restrict__ ws) {
    int row = blockIdx.x, k = threadIdx.x;
    float v = x[row * D_DIM + k];
    __shared__ float red[256];
    red[k] = v * v;
    __syncthreads();
    for (int s = 128; s > 0; s >>= 1) {
        if (k < s) red[k] += red[k + s];
        __syncthreads();
    }
    if (k == 0) ws[WS_XSQ + row] = red[0];
}

// ---------- lexicographic (value, index) compare-exchange helpers ----------
__device__ __forceinline__ void lexCE(float& av, int& ai, float& bv, int& bi) {
    bool sw = (bv < av) || ((bv == av) && (bi < ai));
    float nv0 = sw ? bv : av; int ni0 = sw ? bi : ai;
    float nv1 = sw ? av : bv; int ni1 = sw ? ai : bi;
    av = nv0; ai = ni0; bv = nv1; bi = ni1;
}

__device__ __forceinline__ void merge4(
    float& a0v, int& a0i, float& a1v, int& a1i,
    float& a2v, int& a2i, float& a3v, int& a3i,
    float b0v, int b0i, float b1v, int b1i,
    float b2v, int b2i, float b3v, int b3i)
{
    bool s0 = (b3v < a0v) || ((b3v == a0v) && (b3i < a0i));
    float m0v = s0 ? b3v : a0v; int m0i = s0 ? b3i : a0i;
    bool s1 = (b2v < a1v) || ((b2v == a1v) && (b2i < a1i));
    float m1v = s1 ? b2v : a1v; int m1i = s1 ? b2i : a1i;
    bool s2 = (b1v < a2v) || ((b1v == a2v) && (b1i < a2i));
    float m2v = s2 ? b1v : a2v; int m2i = s2 ? b1i : a2i;
    bool s3 = (b0v < a3v) || ((b0v == a3v) && (b0i < a3i));
    float m3v = s3 ? b0v : a3v; int m3i = s3 ? b0i : a3i;
    lexCE(m0v, m0i, m2v, m2i);
    lexCE(m1v, m1i, m3v, m3i);
    lexCE(m0v, m0i, m1v, m1i);
    lexCE(m2v, m2i, m3v, m3i);
    a0v = m0v; a0i = m0i; a1v = m1v; a1i = m1i;
    a2v = m2v; a2i = m2i; a3v = m3v; a3i = m3i;
}

// ---------- K1: fused GEMM + register top-4, 512 threads, reg-prefetch ----------
__global__ __launch_bounds__(512, 4) void gemm_topk(
    const float* __restrict__ x, const float* __restrict__ ws,
    float* __restrict__ out_topk, unsigned* __restrict__ counts)
{
    __shared__ float As[BK * ASTRIDE];   // 16 x 132 (128 rows used)
    __shared__ float Bs[BK * BN];        // 16 x 128
    __shared__ unsigned hist[512];

    const int tid = threadIdx.x;
    const int tx = tid & 15, ty = tid >> 4;   // ty: 0..31, 4 rows each
    const int rowBase = blockIdx.x * BM;
    const float* dictT = ws + WS_DICTT;
    const float* dsq = ws + WS_DSQ;
    const float* xsq = ws + WS_XSQ;

    // staging coords (one float4 each for A and B per kb)
    const int ar = tid >> 2;             // 0..127 row
    const int akk = (tid & 3) << 2;      // 0,4,8,12
    const int bk = tid >> 5;             // 0..15 k
    const int bc4 = (tid & 31) << 2;     // 0..124 col

    if (tid < 512) hist[tid] = 0u;

    float rv0 = 3.4e38f, rv1 = 3.4e38f, rv2 = 3.4e38f, rv3 = 3.4e38f;
    int ri0 = 0x7FFFFFFF, ri1 = 0x7FFFFFFF, ri2 = 0x7FFFFFFF, ri3 = 0x7FFFFFFF;

    for (int cc = 0; cc < C_CLUST / BN; ++cc) {
        float acc[4][8];
        #pragma unroll
        for (int i = 0; i < 4; ++i)
            #pragma unroll
            for (int j = 0; j < 8; ++j) acc[i][j] = 0.f;

        // prefetch kb=0 into registers
        float4 va = *reinterpret_cast<const float4*>(
            &x[(rowBase + ar) * D_DIM + akk]);
        float4 vb = *reinterpret_cast<const float4*>(
            &dictT[bk * C_CLUST + cc * BN + bc4]);

        for (int kb = 0; kb < D_DIM / BK; ++kb) {
            __syncthreads();   // previous compute done reading LDS
            As[(akk + 0) * ASTRIDE + ar] = va.x;
            As[(akk + 1) * ASTRIDE + ar] = va.y;
            As[(akk + 2) * ASTRIDE + ar] = va.z;
            As[(akk + 3) * ASTRIDE + ar] = va.w;
            *reinterpret_cast<float4*>(&Bs[bk * BN + bc4]) = vb;
            __syncthreads();
            if (kb + 1 < D_DIM / BK) {   // prefetch next tile (hides under FMA)
                va = *reinterpret_cast<const float4*>(
                    &x[(rowBase + ar) * D_DIM + (kb + 1) * BK + akk]);
                vb = *reinterpret_cast<const float4*>(
                    &dictT[((kb + 1) * BK + bk) * C_CLUST + cc * BN + bc4]);
            }
            #pragma unroll
            for (int k = 0; k < BK; ++k) {
                float a[4], b[8];
                float4 t0 = *reinterpret_cast<const float4*>(&As[k * ASTRIDE + ty * 4]);
                float4 u0 = *reinterpret_cast<const float4*>(&Bs[k * BN + tx * 4]);
                float4 u1 = *reinterpret_cast<const float4*>(&Bs[k * BN + 64 + tx * 4]);
                a[0]=t0.x; a[1]=t0.y; a[2]=t0.z; a[3]=t0.w;
                b[0]=u0.x; b[1]=u0.y; b[2]=u0.z; b[3]=u0.w;
                b[4]=u1.x; b[5]=u1.y; b[6]=u1.z; b[7]=u1.w;
                #pragma unroll
                for (int i = 0; i < 4; ++i)
                    #pragma unroll
                    for (int j = 0; j < 8; ++j)
                        acc[i][j] = fmaf(a[i], b[j], acc[i][j]);
            }
        }

        // ---- epilogue: per-row top-4 in registers ----
        float ds[8];
        #pragma unroll
        for (int j = 0; j < 8; ++j) {
            int col = (j < 4) ? (tx * 4 + j) : (64 + tx * 4 + (j - 4));
            ds[j] = dsq[cc * BN + col];
        }
        #pragma unroll
        for (int i = 0; i < 4; ++i) {
            float xs = xsq[rowBase + ty * 4 + i];
            float l0v = 3.4e38f, l1v = 3.4e38f, l2v = 3.4e38f, l3v = 3.4e38f;
            int l0i = 0x7FFFFFFF, l1i = 0x7FFFFFFF, l2i = 0x7FFFFFFF, l3i = 0x7FFFFFFF;
            #pragma unroll
            for (int j = 0; j < 8; ++j) {
                int col = (j < 4) ? (tx * 4 + j) : (64 + tx * 4 + (j - 4));
                int idx = cc * BN + col;
                float v = __fsub_rn(__fadd_rn(xs, ds[j]),
                                    __fmul_rn(2.0f, acc[i][j]));
                if (v < l3v) {
                    if (v < l2v) {
                        l3v = l2v; l3i = l2i;
                        if (v < l1v) {
                            l2v = l1v; l2i = l1i;
                            if (v < l0v) { l1v = l0v; l1i = l0i; l0v = v; l0i = idx; }
                            else { l1v = v; l1i = idx; }
                        } else { l2v = v; l2i = idx; }
                    } else { l3v = v; l3i = idx; }
                }
            }
            #pragma unroll
            for (int mask = 1; mask <= 8; mask <<= 1) {
                float b0v = __shfl_xor(l0v, mask); int b0i = __shfl_xor(l0i, mask);
                float b1v = __shfl_xor(l1v, mask); int b1i = __shfl_xor(l1i, mask);
                float b2v = __shfl_xor(l2v, mask); int b2i = __shfl_xor(l2i, mask);
                float b3v = __shfl_xor(l3v, mask); int b3i = __shfl_xor(l3i, mask);
                merge4(l0v, l0i, l1v, l1i, l2v, l2i, l3v, l3i,
                       b0v, b0i, b1v, b1i, b2v, b2i, b3v, b3i);
            }
            if ((tx & 3) == i)
                merge4(rv0, ri0, rv1, ri1, rv2, ri2, rv3, ri3,
                       l0v, l0i, l1v, l1i, l2v, l2i, l3v, l3i);
        }
    }

    if (tx < 4) {
        int r = rowBase + ty * 4 + tx;
        out_topk[r * 4 + 0] = (float)ri0;
        out_topk[r * 4 + 1] = (float)ri1;
        out_topk[r * 4 + 2] = (float)ri2;
        out_topk[r * 4 + 3] = (float)ri3;
        atomicAdd(&hist[ri0], 1u);
        atomicAdd(&hist[ri1], 1u);
        atomicAdd(&hist[ri2], 1u);
        atomicAdd(&hist[ri3], 1u);
    }
    __syncthreads();
    if (tid < 512) {
        unsigned v = hist[tid];
        if (v) atomicAdd(&counts[tid], v);
    }
}

// ---------- K2: group_emb, grid-stride float4 ----------
__global__ __launch_bounds__(256) void group_emb_k(
    const float* __restrict__ x, const float* __restrict__ dic,
    const float* __restrict__ topk, float* __restrict__ out)
{
    const int stride = gridDim.x * blockDim.x;
    for (int gid = blockIdx.x * blockDim.x + threadIdx.x;
         gid < N_ROWS * (D_DIM / 4); gid += stride) {
        int row = gid >> 6;          // 64 float4s per row
        int d4 = (gid & 63) << 2;
        int i0 = (int)topk[row * 4 + 0];
        int i1 = (int)topk[row * 4 + 1];
        int i2 = (int)topk[row * 4 + 2];
        int i3 = (int)topk[row * 4 + 3];
        float4 a = *reinterpret_cast<const float4*>(&dic[i0 * D_DIM + d4]);
        float4 b = *reinterpret_cast<const float4*>(&dic[i1 * D_DIM + d4]);
        float4 c = *reinterpret_cast<const float4*>(&dic[i2 * D_DIM + d4]);
        float4 e = *reinterpret_cast<const float4*>(&dic[i3 * D_DIM + d4]);
        float4 xv = *reinterpret_cast<const float4*>(&x[row * D_DIM + d4]);
        float4 o;
        {
            float g = __fmul_rn(__fadd_rn(__fadd_rn(__fadd_rn(a.x, b.x), c.x), e.x), 0.25f);
            o.x = __fadd_rn(__fsub_rn(g, xv.x), xv.x);
        }
        {
            float g = __fmul_rn(__fadd_rn(__fadd_rn(__fadd_rn(a.y, b.y), c.y), e.y), 0.25f);
            o.y = __fadd_rn(__fsub_rn(g, xv.y), xv.y);
        }
        {
            float g = __fmul_rn(__fadd_rn(__fadd_rn(__fadd_rn(a.z, b.z), c.z), e.z), 0.25f);
            o.z = __fadd_rn(__fsub_rn(g, xv.z), xv.z);
        }
        {
            float g = __fmul_rn(__fadd_rn(__fadd_rn(__fadd_rn(a.w, b.w), c.w), e.w), 0.25f);
            o.w = __fadd_rn(__fsub_rn(g, xv.w), xv.w);
        }
        *reinterpret_cast<float4*>(&out[row * D_DIM + d4]) = o;
    }
}

// ---------- K3: exclusive prefix sum of counts ----------
__global__ void prefix_k(const unsigned* __restrict__ counts, unsigned* __restrict__ offsets) {
    __shared__ unsigned s[512];
    int t = threadIdx.x;
    unsigned my = counts[t];
    s[t] = my;
    __syncthreads();
    for (int off = 1; off < 512; off <<= 1) {
        unsigned v = (t >= off) ? s[t - off] : 0u;
        __syncthreads();
        s[t] += v;
        __syncthreads();
    }
    offsets[t] = s[t] - my;
    if (t == 511) offsets[512] = s[511];
}

// ---------- K4: scatter rows into cluster buckets (packed (c<<16)|row) ----------
__global__ void scatter_k(const float* __restrict__ topk, const unsigned* __restrict__ offsets,
                          unsigned* __restrict__ fill, unsigned* __restrict__ rowlist) {
    int row = blockIdx.x * 256 + threadIdx.x;
    #pragma unroll
    for (int k = 0; k < 4; ++k) {
        int c = (int)topk[row * 4 + k];
        unsigned p = atomicAdd(&fill[c], 1u);
        rowlist[offsets[c] + p] = ((unsigned)c << 16) | (unsigned)row;
    }
}

// ---------- K5: load-balanced segmented sum (encodings^T @ X) ----------
__global__ __launch_bounds__(256, 8) void cluster_sum2_k(
    const float* __restrict__ x, const unsigned* __restrict__ rowlist,
    float* __restrict__ isum)
{
    const int d = threadIdx.x;
    const int base = blockIdx.x * RPB;
    unsigned e0 = rowlist[base];
    int ccur = (int)(e0 >> 16);
    float acc = 0.f;
    #pragma unroll 4
    for (int j = 0; j < RPB; ++j) {
        unsigned e = rowlist[base + j];
        int c = (int)(e >> 16);
        float v = x[(e & 0xFFFFu) * D_DIM + d];
        if (c != ccur) {
            atomicAdd(&isum[ccur * D_DIM + d], acc);
            acc = 0.f;
            ccur = c;
        }
        acc += v;
    }
    atomicAdd(&isum[ccur * D_DIM + d], acc);
}

// ---------- K6: sequential decay scan + css EMA + laplace ----------
__global__ void ema_scalar_k(const float* __restrict__ css_in, const float* __restrict__ cnum_in,
                             const unsigned* __restrict__ counts,
                             float* __restrict__ ws, float* __restrict__ out) {
    __shared__ float sdecay[512];
    __shared__ float sred[512];
    __shared__ float scn[512];
    __shared__ unsigned smask[512];
    int t = threadIdx.x; // 512 threads
    unsigned cnt = counts[t];
    float size = (float)cnt;
    float mask = (cnt != 0u) ? 1.f : 0.f;
    float cnum_new = __fadd_rn(cnum_in[t], mask);
    scn[t] = cnum_new;
    smask[t] = cnt;
    __syncthreads();
    if (t == 0) {
        float d = 0.99f;
        for (int c = 0; c < 512; ++c) {
            if (smask[c] != 0u && scn[c] <= 10.0f)
                d = __fmul_rn(d, scn[c]) / 10.0f;   // (decay*c)/10, IEEE div
            sdecay[c] = d;
        }
    }
    __syncthreads();
    float d = sdecay[t];
    float css = css_in[t];
    float css_new = (cnt != 0u)
        ? __fadd_rn(__fmul_rn(css, d), __fmul_rn(size, __fsub_rn(1.f, d)))
        : css;
    out[OUT_CSS + t] = css_new;
    out[OUT_CNUM + t] = cnum_new;
    sred[t] = css_new;
    __syncthreads();
    for (int s = 256; s > 0; s >>= 1) {
        if (t < s) sred[t] += sred[t + s];
        __syncthreads();
    }
    float S = sred[0];
    float cs = __fmul_rn(__fdiv_rn(__fadd_rn(css_new, 1e-5f),
                                   __fadd_rn(S, 0.00512f)), S);
    ws[WS_CS + t] = cs;
    ws[WS_DCY + t] = d;
}

// ---------- K7: cluster_value EMA + dictionary normalize ----------
__global__ void final_k(const float* __restrict__ cv_in, const float* __restrict__ ws,
                        const unsigned* __restrict__ counts, float* __restrict__ out) {
    int c = blockIdx.x, d = threadIdx.x;
    float isum = ws[WS_ISUM + c * D_DIM + d];
    float dc = ws[WS_DCY + c];
    float cs = ws[WS_CS + c];
    unsigned cnt = counts[c];
    float cv = cv_in[c * D_DIM + d];
    float cvn = (cnt != 0u)
        ? __fadd_rn(__fmul_rn(cv, dc), __fmul_rn(isum, __fsub_rn(1.f, dc)))
        : cv;
    out[OUT_CV + c * D_DIM + d] = cvn;
    out[OUT_DICT + c * D_DIM + d] = (cnt != 0u) ? __fdiv_rn(cvn, cs) : cvn;
}

extern "C" void kernel_launch(void* const* d_in, const int* in_sizes, int n_in,
                              void* d_out, int out_size, void* d_ws, size_t ws_size,
                              hipStream_t stream) {
    const float* x       = (const float*)d_in[0];
    const float* dic     = (const float*)d_in[1];
    const float* css_in  = (const float*)d_in[2];
    const float* cv_in   = (const float*)d_in[3];
    const float* cnum_in = (const float*)d_in[4];
    float* out = (float*)d_out;
    float* ws  = (float*)d_ws;
    unsigned* counts  = (unsigned*)(ws + WS_COUNTS);
    unsigned* offsets = (unsigned*)(ws + WS_OFFSETS);
    unsigned* fill    = (unsigned*)(ws + WS_FILL);
    unsigned* rowlist = (unsigned*)(ws + WS_ROWLIST);

    zero_k<<<C_CLUST * D_DIM / 256, 256, 0, stream>>>(counts, fill, ws + WS_ISUM);
    prep_dict<<<C_CLUST, 256, 0, stream>>>(dic, ws);
    row_sq<<<N_ROWS, 256, 0, stream>>>(x, ws);

    gemm_topk<<<N_ROWS / BM, 512, 0, stream>>>(x, ws, out + OUT_TOPK, counts);

    group_emb_k<<<4096, 256, 0, stream>>>(x, dic, out + OUT_TOPK, out + OUT_GEMB);
    prefix_k<<<1, 512, 0, stream>>>(counts, offsets);
    scatter_k<<<N_ROWS / 256, 256, 0, stream>>>(out + OUT_TOPK, offsets, fill, rowlist);
    cluster_sum2_k<<<N_ROWS * 4 / RPB, 256, 0, stream>>>(x, rowlist, ws + WS_ISUM);
    ema_scalar_k<<<1, 512, 0, stream>>>(css_in, cnum_in, counts, ws, out);
    final_k<<<C_CLUST, 256, 0, stream>>>(cv_in, ws, counts, out);
}